// Round 19
// baseline (160.825 us; speedup 1.0000x reference)
//
#include <hip/hip_runtime.h>
#include <hip/hip_bf16.h>
#include <type_traits>

#define EPS 1e-5f

typedef _Float16 half8 __attribute__((ext_vector_type(8)));
typedef _Float16 half4 __attribute__((ext_vector_type(4)));
typedef _Float16 half2v __attribute__((ext_vector_type(2)));
typedef float f32x4 __attribute__((ext_vector_type(4)));

__device__ __forceinline__ void gload_lds16(const void* gsrc, void* ldst) {
  __builtin_amdgcn_global_load_lds(
      (const __attribute__((address_space(1))) void*)gsrc,
      (__attribute__((address_space(3))) void*)ldst, 16, 0, 0);
}

// ---------------------------------------------------------------- fold bn + f16 weights + mask A-frags
__global__ __launch_bounds__(256) void fold_k(
    const float* __restrict__ w1, const float* __restrict__ g1, const float* __restrict__ b1,
    const float* __restrict__ m1, const float* __restrict__ v1,
    const float* __restrict__ wc,
    const float* __restrict__ g2, const float* __restrict__ b2,
    const float* __restrict__ m2, const float* __restrict__ v2,
    const float* __restrict__ w2, const float* __restrict__ g3, const float* __restrict__ b3,
    const float* __restrict__ m3, const float* __restrict__ v3,
    const float* __restrict__ we,
    _Float16* __restrict__ w1h, float* __restrict__ bias1,
    _Float16* __restrict__ wch,
    _Float16* __restrict__ w2h, float* __restrict__ bias3,
    float* __restrict__ s2, float* __restrict__ t2,
    _Float16* __restrict__ wa) {
  int i = blockIdx.x * 256 + threadIdx.x;
  if (i < 384 * 64) {
    int o = i >> 6;
    float inv = g1[o] / sqrtf(v1[o] + EPS);
    w1h[i] = (_Float16)(w1[i] * inv);
  }
  if (i < 64 * 384) wch[i] = (_Float16)wc[i];
  if (i < 128 * 384) {
    int o = i / 384;
    float inv = g3[o] / sqrtf(v3[o] + EPS);
    w2h[i] = (_Float16)(w2[i] * inv);
  }
  if (i < 384) {
    float inv = g1[i] / sqrtf(v1[i] + EPS);
    bias1[i] = b1[i] - m1[i] * inv;
    float inv2 = g2[i] / sqrtf(v2[i] + EPS);
    s2[i] = inv2;
    t2[i] = b2[i] - m2[i] * inv2;
  }
  if (i < 128) {
    float inv = g3[i] / sqrtf(v3[i] + EPS);
    bias3[i] = b3[i] - m3[i] * inv;
  }
  if (i < 51200) {
    int j = i & 7;
    int lane = (i >> 3) & 63;
    int f = i >> 9;             // 0..99
    int ocf = f & 1;
    int tap = (f >> 1) % 25;
    int ph = f / 50;
    int oc = ocf * 16 + (lane & 15);
    int cm = ph * 32 + (lane >> 4) * 8 + j;
    float v = (oc < 25) ? we[((size_t)oc * 64 + cm) * 25 + tap] : 0.f;
    wa[i] = (_Float16)v;
  }
}

// ---------------------------------------------------------------- 1x1 conv via f16 MFMA (r14 config)
// 32-row K-steps, global_load_lds staging (linear LDS dest, pre-swizzled
// source); xs/oT LDS union; XCD-group swizzled 1D grid.
template <int IC, int NPF, int ACT, int NOC, int NPXT, typename TI, typename TO>
__global__ __launch_bounds__(256) void gemm16_k(
    const TI* __restrict__ in, const _Float16* __restrict__ wh,
    const float* __restrict__ bias, TO* __restrict__ out, int npx) {
  constexpr int BPX = NPF * 64;
  constexpr int V = 16 / sizeof(TI);
  constexpr int CPR = BPX / V;
  constexpr int SPT = 32 * CPR / 256;
  constexpr int PAD = 16 / sizeof(TO);
  constexpr int CH = 16 / sizeof(TO);
  constexpr int SPAN = NPF * 16;
  constexpr int LPO = SPAN / CH;
  constexpr int OCPI = 64 / LPO;
  constexpr size_t XS_B = (size_t)32 * BPX * sizeof(TI);
  constexpr size_t OT_B = (size_t)64 * (BPX + PAD) * sizeof(TO);
  constexpr size_t SM_B = XS_B > OT_B ? XS_B : OT_B;
  using vec16 = std::conditional_t<std::is_same_v<TO, _Float16>, half8, float4>;

  __shared__ __align__(16) unsigned char smem[SM_B];
  TI (*xs)[BPX] = (TI (*)[BPX])smem;
  TO (*oT)[BPX + PAD] = (TO (*)[BPX + PAD])smem;

  const int tid = threadIdx.x;
  const int lane = tid & 63;
  const int w = tid >> 6;
  const int l15 = lane & 15;
  const int g = lane >> 4;
  const int wpx = w * SPAN;

  // swizzled block decode
  const int wg = blockIdx.x;
  const int xcd = wg & 7;
  const int s = wg >> 3;
  const int oct = s % NOC;
  const int gl = s / NOC;
  const int grp = gl * 8 + xcd;
  const int pxt = grp % NPXT;
  const int b = grp / NPXT;

  const int p0 = pxt * BPX;
  const int oc0 = oct * 64;
  const int OCT = NOC * 64;
  const TI* inb = in + (size_t)b * IC * npx + p0;

  f32x4 acc[4][NPF];
#pragma unroll
  for (int fo = 0; fo < 4; ++fo)
#pragma unroll
    for (int pf = 0; pf < NPF; ++pf)
      acc[fo][pf] = (f32x4){0.f, 0.f, 0.f, 0.f};

  for (int kk = 0; kk < IC; kk += 32) {
    __syncthreads();
    half8 a[4];
#pragma unroll
    for (int fo = 0; fo < 4; ++fo)
      a[fo] = *(const half8*)&wh[(size_t)(oc0 + fo * 16 + l15) * IC + kk + g * 8];
#pragma unroll
    for (int i = 0; i < SPT; ++i) {
      int sl = tid + 256 * i;
      int k = sl / CPR, q = sl - (sl / CPR) * CPR;
      int qg = q ^ (((k >> 3) & 1) << 2);
      gload_lds16(&inb[(size_t)(kk + k) * npx + qg * V],
                  (unsigned char*)smem + (size_t)sl * 16);
    }
    __syncthreads();
    half8 xb[NPF];
#pragma unroll
    for (int pf = 0; pf < NPF; ++pf) {
      const int px = wpx + pf * 16 + l15;
      const int q = px / V, e = px - (px / V) * V;
      const int col = (q ^ ((g & 1) << 2)) * V + e;
#pragma unroll
      for (int j = 0; j < 8; ++j)
        xb[pf][j] = (_Float16)xs[g * 8 + j][col];
    }
#pragma unroll
    for (int fo = 0; fo < 4; ++fo)
#pragma unroll
      for (int pf = 0; pf < NPF; ++pf)
        acc[fo][pf] = __builtin_amdgcn_mfma_f32_16x16x32_f16(
            a[fo], xb[pf], acc[fo][pf], 0, 0, 0);
  }
  __syncthreads();  // xs dead; smem becomes oT

  // epilogue: bias/act -> per-wave LDS transpose -> 16B vectorized stores
#pragma unroll
  for (int fo = 0; fo < 4; ++fo) {
#pragma unroll
    for (int r = 0; r < 4; ++r) {
      float bz = bias[oc0 + fo * 16 + g * 4 + r];
#pragma unroll
      for (int pf = 0; pf < NPF; ++pf) {
        float v = acc[fo][pf][r] + bz;
        if (ACT) v = fminf(fmaxf(v, 0.f), 6.f);
        oT[fo * 16 + g * 4 + r][wpx + pf * 16 + l15] = (TO)v;
      }
    }
  }
#pragma unroll
  for (int i = 0; i < LPO; ++i) {
    int oc = i * OCPI + lane / LPO;
    int pxo = (lane % LPO) * CH;
    vec16 v = *(const vec16*)&oT[oc][wpx + pxo];
    *(vec16*)&out[((size_t)b * OCT + oc0 + oc) * npx + p0 + wpx + pxo] = v;
  }
}

// ---------------------------------------------------------------- mask conv 5x5 s2 via MFMA + fused softmax
__global__ __launch_bounds__(256) void mask_conv6_k(
    const _Float16* __restrict__ y, const _Float16* __restrict__ wa,
    const float* __restrict__ be, float* __restrict__ msk) {
  __shared__ _Float16 ysh[32][5][136];
  __shared__ float lsm[32][66];
  const int ho = blockIdx.x;
  const int b = blockIdx.y;
  const int tid = threadIdx.x;
  const int lane = tid & 63;
  const int w = tid >> 6;
  const int l15 = lane & 15;
  const int g = lane >> 4;
  const int wo = w * 16 + l15;
  const int woe = (wo < 56) ? wo : 55;
  const int ci0 = 2 * woe + 6;

  for (int i = tid; i < 640; i += 256) {
    int ch = i / 20; int rem = i - ch * 20; int ri = rem / 4; int q = rem & 3;
    *(uint*)&ysh[ch][ri][q * 2] = 0u;
  }
  for (int i = tid; i < 1280; i += 256) {
    int ch = i / 40; int rem = i - ch * 40; int ri = rem / 8; int q = rem & 7;
    *(uint*)&ysh[ch][ri][120 + q * 2] = 0u;
  }

  f32x4 acc[2] = {(f32x4){0.f, 0.f, 0.f, 0.f}, (f32x4){0.f, 0.f, 0.f, 0.f}};

  for (int ph = 0; ph < 2; ++ph) {
    __syncthreads();
    for (int i = tid; i < 2240; i += 256) {
      int ch = i / 70;
      int rem = i - ch * 70;
      int ri = rem / 14;
      int j8 = rem - ri * 14;
      int hi = 2 * ho - 2 + ri;
      half8 v = {0, 0, 0, 0, 0, 0, 0, 0};
      if ((unsigned)hi < 112u)
        v = *(const half8*)&y[((size_t)(b * 64 + ph * 32 + ch) * 112 + hi) * 112 + j8 * 8];
      *(half8*)&ysh[ch][ri][8 + j8 * 8] = v;
    }
    __syncthreads();

    const _Float16* wap = wa + (size_t)ph * 25600;
#pragma unroll
    for (int di = 0; di < 5; ++di) {
      half2v pa[8], pb[8];
      _Float16 pc[8];
#pragma unroll
      for (int j = 0; j < 8; ++j) {
        pa[j] = *(const half2v*)&ysh[g * 8 + j][di][ci0];
        pb[j] = *(const half2v*)&ysh[g * 8 + j][di][ci0 + 2];
        pc[j] = ysh[g * 8 + j][di][ci0 + 4];
      }
#pragma unroll
      for (int dj = 0; dj < 5; ++dj) {
        half8 bf;
#pragma unroll
        for (int j = 0; j < 8; ++j)
          bf[j] = (dj == 0) ? pa[j][0]
                : (dj == 1) ? pa[j][1]
                : (dj == 2) ? pb[j][0]
                : (dj == 3) ? pb[j][1]
                            : pc[j];
        const int tap = di * 5 + dj;
        half8 a0 = *(const half8*)&wap[(tap * 2 + 0) * 512 + lane * 8];
        half8 a1 = *(const half8*)&wap[(tap * 2 + 1) * 512 + lane * 8];
        acc[0] = __builtin_amdgcn_mfma_f32_16x16x32_f16(a0, bf, acc[0], 0, 0, 0);
        acc[1] = __builtin_amdgcn_mfma_f32_16x16x32_f16(a1, bf, acc[1], 0, 0, 0);
      }
    }
  }

#pragma unroll
  for (int ocf = 0; ocf < 2; ++ocf)
#pragma unroll
    for (int r = 0; r < 4; ++r)
      lsm[ocf * 16 + g * 4 + r][w * 16 + l15] = acc[ocf][r];
  __syncthreads();

  if (tid < 56) {
    float v[25];
    float mx = -1e30f;
#pragma unroll
    for (int k = 0; k < 25; ++k) {
      float s = lsm[k][tid] + be[k];
      v[k] = s;
      mx = fmaxf(mx, s);
    }
    float s = 0.f;
#pragma unroll
    for (int k = 0; k < 25; ++k) {
      v[k] = __expf(v[k] - mx);
      s += v[k];
    }
    float inv = 1.0f / s;
#pragma unroll
    for (int k = 0; k < 25; ++k)
      msk[((size_t)b * 25 + k) * 3136 + ho * 56 + tid] = v[k] * inv;
  }
}

// ---------------------------------------------------------------- carafe (f16 h in, f16 h2 out)
__device__ __forceinline__ void stage_pair(float dst[2][19][120],
                                           const _Float16* __restrict__ hbase,
                                           int ho0, int tid) {
  for (int i = tid; i < 2 * 19 * 14; i += 512) {
    int ch = i / 266;
    int rem = i - ch * 266;
    int rr = rem / 14;
    int j8 = rem - rr * 14;
    int hi = 2 * ho0 - 2 + rr;
    float4 lo = {0.f, 0.f, 0.f, 0.f}, hi4 = {0.f, 0.f, 0.f, 0.f};
    if ((unsigned)hi < 112u) {
      half8 v = *(const half8*)&hbase[(size_t)ch * 12544 + hi * 112 + j8 * 8];
      lo = (float4){(float)v[0], (float)v[1], (float)v[2], (float)v[3]};
      hi4 = (float4){(float)v[4], (float)v[5], (float)v[6], (float)v[7]};
    }
    *(float4*)&dst[ch][rr][4 + j8 * 8] = lo;
    *(float4*)&dst[ch][rr][8 + j8 * 8] = hi4;
  }
}

__global__ __launch_bounds__(512) void carafe3_k(
    const _Float16* __restrict__ h, const float* __restrict__ msk,
    const float* __restrict__ s2, const float* __restrict__ t2,
    _Float16* __restrict__ h2) {
  __shared__ float ys[2][2][19][120];
  const int hx = blockIdx.x;
  const int b  = blockIdx.y;
  const int cz = blockIdx.z;
  const int ho0 = hx * 8;
  const int tid = threadIdx.x;
  const int r = tid / 56;
  const int c = tid - r * 56;
  const int c0 = cz * 24;

  for (int i = tid; i < 2 * 2 * 19 * 8; i += 512) {
    int bufi = i / 304;
    int rem = i - bufi * 304;
    int ch = rem / 152;
    int rem2 = rem - ch * 152;
    int rr = rem2 / 8;
    int p = rem2 - rr * 8;
    int col = (p < 4) ? p : (112 + p);
    ys[bufi][ch][rr][col] = 0.f;
  }

  float m[25];
  if (tid < 448) {
    const float* mp = msk + (size_t)b * 25 * 3136 + (ho0 + r) * 56 + c;
#pragma unroll
    for (int k = 0; k < 25; ++k) m[k] = mp[(size_t)k * 3136];
  }
  __syncthreads();

  stage_pair(ys[0], h + (size_t)(b * 384 + c0) * 12544, ho0, tid);
  __syncthreads();

#pragma unroll
  for (int p = 0; p < 12; ++p) {
    const int bf = p & 1;
    if (p + 1 < 12)
      stage_pair(ys[bf ^ 1], h + (size_t)(b * 384 + c0 + 2 * (p + 1)) * 12544,
                 ho0, tid);
    if (tid < 448) {
#pragma unroll
      for (int cl = 0; cl < 2; ++cl) {
        const int cc = c0 + 2 * p + cl;
        float acc = 0.f;
#pragma unroll
        for (int di = 0; di < 5; ++di) {
          const float* row = &ys[bf][cl][2 * r + di][2 * c + 2];
          float2 a01 = *(const float2*)&row[0];
          float2 a23 = *(const float2*)&row[2];
          float a4 = row[4];
          acc = fmaf(a01.x, m[di * 5 + 0], acc);
          acc = fmaf(a01.y, m[di * 5 + 1], acc);
          acc = fmaf(a23.x, m[di * 5 + 2], acc);
          acc = fmaf(a23.y, m[di * 5 + 3], acc);
          acc = fmaf(a4,    m[di * 5 + 4], acc);
        }
        float o = s2[cc] * acc + t2[cc];
        h2[((size_t)(b * 384 + cc) * 56 + ho0 + r) * 56 + c] =
            (_Float16)fminf(fmaxf(o, 0.f), 6.f);
      }
    }
    __syncthreads();
  }
}

// ---------------------------------------------------------------- launch
extern "C" void kernel_launch(void* const* d_in, const int* in_sizes, int n_in,
                              void* d_out, int out_size, void* d_ws, size_t ws_size,
                              hipStream_t stream) {
  const float* x  = (const float*)d_in[0];
  const float* w1 = (const float*)d_in[1];
  const float* g1 = (const float*)d_in[2];
  const float* b1 = (const float*)d_in[3];
  const float* m1 = (const float*)d_in[4];
  const float* v1 = (const float*)d_in[5];
  const float* wc = (const float*)d_in[6];
  const float* bc = (const float*)d_in[7];
  const float* we = (const float*)d_in[8];
  const float* be = (const float*)d_in[9];
  const float* g2 = (const float*)d_in[10];
  const float* b2 = (const float*)d_in[11];
  const float* m2 = (const float*)d_in[12];
  const float* v2 = (const float*)d_in[13];
  const float* w2 = (const float*)d_in[14];
  const float* g3 = (const float*)d_in[15];
  const float* b3 = (const float*)d_in[16];
  const float* m3 = (const float*)d_in[17];
  const float* v3 = (const float*)d_in[18];
  float* out = (float*)d_out;

  // workspace layout
  _Float16* hq  = (_Float16*)d_ws;          // 38,535,168 halves
  _Float16* yq  = hq + 38535168;            //  6,422,528 halves
  _Float16* h2q = yq + 6422528;             //  9,633,792 halves
  float* mskf   = (float*)(h2q + 9633792);  //    627,200 floats
  float* bias1  = mskf + 627200;            // 384
  float* bias3  = bias1 + 384;              // 128
  float* s2     = bias3 + 128;              // 384
  float* t2     = s2 + 384;                 // 384
  _Float16* w1h = (_Float16*)(t2 + 384);    // 24576 halves
  _Float16* wch = w1h + 24576;              // 24576 halves
  _Float16* w2h = wch + 24576;              // 49152 halves
  _Float16* wa  = w2h + 49152;              // 51200 halves (MFMA A-frags)

  fold_k<<<200, 256, 0, stream>>>(w1, g1, b1, m1, v1, wc, g2, b2, m2, v2,
                                  w2, g3, b3, m3, v3, we,
                                  w1h, bias1, wch, w2h, bias3, s2, t2, wa);

  // stage 1: h = relu6(bn1(conv1x1(x, w1)))  [fp32 in, f16 out]
  gemm16_k<64, 2, 1, 6, 98, float, _Float16>
      <<<6 * 98 * 8, 256, 0, stream>>>(x, w1h, bias1, hq, 12544);

  // compressor: y = conv1x1(h, wc) + bc  [f16 in, f16 out]
  // NPF=1: grid 1568 (6.1 blocks/CU) — was 784 (grid-capped at 3/CU)
  gemm16_k<384, 1, 0, 1, 196, _Float16, _Float16>
      <<<1 * 196 * 8, 256, 0, stream>>>(hq, wch, bc, yq, 12544);

  // mask conv via MFMA + in-kernel softmax
  mask_conv6_k<<<dim3(56, 8), 256, 0, stream>>>(yq, wa, be, mskf);

  // carafe + bn2 + relu6  [f16 in/out]
  carafe3_k<<<dim3(7, 8, 16), 512, 0, stream>>>(hq, mskf, s2, t2, h2q);

  // final: out = bn3(conv1x1(h2, w2))  [f16 in, fp32 out]
  gemm16_k<384, 1, 0, 2, 49, _Float16, float>
      <<<2 * 49 * 8, 256, 0, stream>>>(h2q, w2h, bias3, out, 3136);
}

// Round 20
// 146.479 us; speedup vs baseline: 1.0979x; 1.0979x over previous
//
#include <hip/hip_runtime.h>
#include <hip/hip_bf16.h>
#include <type_traits>

#define EPS 1e-5f

typedef _Float16 half8 __attribute__((ext_vector_type(8)));
typedef _Float16 half4 __attribute__((ext_vector_type(4)));
typedef _Float16 half2v __attribute__((ext_vector_type(2)));
typedef float f32x4 __attribute__((ext_vector_type(4)));

__device__ __forceinline__ void gload_lds16(const void* gsrc, void* ldst) {
  __builtin_amdgcn_global_load_lds(
      (const __attribute__((address_space(1))) void*)gsrc,
      (__attribute__((address_space(3))) void*)ldst, 16, 0, 0);
}

// ---------------------------------------------------------------- fold bn + f16 weights + mask A-frags
__global__ __launch_bounds__(256) void fold_k(
    const float* __restrict__ w1, const float* __restrict__ g1, const float* __restrict__ b1,
    const float* __restrict__ m1, const float* __restrict__ v1,
    const float* __restrict__ wc,
    const float* __restrict__ g2, const float* __restrict__ b2,
    const float* __restrict__ m2, const float* __restrict__ v2,
    const float* __restrict__ w2, const float* __restrict__ g3, const float* __restrict__ b3,
    const float* __restrict__ m3, const float* __restrict__ v3,
    const float* __restrict__ we,
    _Float16* __restrict__ w1h, float* __restrict__ bias1,
    _Float16* __restrict__ wch,
    _Float16* __restrict__ w2h, float* __restrict__ bias3,
    float* __restrict__ s2, float* __restrict__ t2,
    _Float16* __restrict__ wa) {
  int i = blockIdx.x * 256 + threadIdx.x;
  if (i < 384 * 64) {
    int o = i >> 6;
    float inv = g1[o] / sqrtf(v1[o] + EPS);
    w1h[i] = (_Float16)(w1[i] * inv);
  }
  if (i < 64 * 384) wch[i] = (_Float16)wc[i];
  if (i < 128 * 384) {
    int o = i / 384;
    float inv = g3[o] / sqrtf(v3[o] + EPS);
    w2h[i] = (_Float16)(w2[i] * inv);
  }
  if (i < 384) {
    float inv = g1[i] / sqrtf(v1[i] + EPS);
    bias1[i] = b1[i] - m1[i] * inv;
    float inv2 = g2[i] / sqrtf(v2[i] + EPS);
    s2[i] = inv2;
    t2[i] = b2[i] - m2[i] * inv2;
  }
  if (i < 128) {
    float inv = g3[i] / sqrtf(v3[i] + EPS);
    bias3[i] = b3[i] - m3[i] * inv;
  }
  if (i < 51200) {
    int j = i & 7;
    int lane = (i >> 3) & 63;
    int f = i >> 9;             // 0..99
    int ocf = f & 1;
    int tap = (f >> 1) % 25;
    int ph = f / 50;
    int oc = ocf * 16 + (lane & 15);
    int cm = ph * 32 + (lane >> 4) * 8 + j;
    float v = (oc < 25) ? we[((size_t)oc * 64 + cm) * 25 + tap] : 0.f;
    wa[i] = (_Float16)v;
  }
}

// ---------------------------------------------------------------- 1x1 conv via f16 MFMA (v6 / round-14 best)
// global_load_lds staging (linear LDS dest, pre-swizzled global source);
// xs/oT LDS union; XCD-group swizzled 1D grid.
template <int IC, int NPF, int ACT, int NOC, int NPXT, typename TI, typename TO>
__global__ __launch_bounds__(256) void gemm16_k(
    const TI* __restrict__ in, const _Float16* __restrict__ wh,
    const float* __restrict__ bias, TO* __restrict__ out, int npx) {
  constexpr int BPX = NPF * 64;
  constexpr int V = 16 / sizeof(TI);
  constexpr int CPR = BPX / V;
  constexpr int SPT = 32 * CPR / 256;
  constexpr int PAD = 16 / sizeof(TO);
  constexpr int CH = 16 / sizeof(TO);
  constexpr int SPAN = NPF * 16;
  constexpr int LPO = SPAN / CH;
  constexpr int OCPI = 64 / LPO;
  constexpr size_t XS_B = (size_t)32 * BPX * sizeof(TI);
  constexpr size_t OT_B = (size_t)64 * (BPX + PAD) * sizeof(TO);
  constexpr size_t SM_B = XS_B > OT_B ? XS_B : OT_B;
  using vec16 = std::conditional_t<std::is_same_v<TO, _Float16>, half8, float4>;

  __shared__ __align__(16) unsigned char smem[SM_B];
  TI (*xs)[BPX] = (TI (*)[BPX])smem;
  TO (*oT)[BPX + PAD] = (TO (*)[BPX + PAD])smem;

  const int tid = threadIdx.x;
  const int lane = tid & 63;
  const int w = tid >> 6;
  const int l15 = lane & 15;
  const int g = lane >> 4;
  const int wpx = w * SPAN;

  // swizzled block decode
  const int wg = blockIdx.x;
  const int xcd = wg & 7;
  const int s = wg >> 3;
  const int oct = s % NOC;
  const int gl = s / NOC;
  const int grp = gl * 8 + xcd;
  const int pxt = grp % NPXT;
  const int b = grp / NPXT;

  const int p0 = pxt * BPX;
  const int oc0 = oct * 64;
  const int OCT = NOC * 64;
  const TI* inb = in + (size_t)b * IC * npx + p0;

  f32x4 acc[4][NPF];
#pragma unroll
  for (int fo = 0; fo < 4; ++fo)
#pragma unroll
    for (int pf = 0; pf < NPF; ++pf)
      acc[fo][pf] = (f32x4){0.f, 0.f, 0.f, 0.f};

  for (int kk = 0; kk < IC; kk += 32) {
    __syncthreads();
    half8 a[4];
#pragma unroll
    for (int fo = 0; fo < 4; ++fo)
      a[fo] = *(const half8*)&wh[(size_t)(oc0 + fo * 16 + l15) * IC + kk + g * 8];
    // stage direct to LDS: linear dest (slot*16B), pre-swizzled source chunk
#pragma unroll
    for (int i = 0; i < SPT; ++i) {
      int sl = tid + 256 * i;
      int k = sl / CPR, q = sl - (sl / CPR) * CPR;
      int qg = q ^ (((k >> 3) & 1) << 2);
      gload_lds16(&inb[(size_t)(kk + k) * npx + qg * V],
                  (unsigned char*)smem + (size_t)sl * 16);
    }
    __syncthreads();
    half8 xb[NPF];
#pragma unroll
    for (int pf = 0; pf < NPF; ++pf) {
      const int px = wpx + pf * 16 + l15;
      const int q = px / V, e = px - (px / V) * V;
      const int col = (q ^ ((g & 1) << 2)) * V + e;
#pragma unroll
      for (int j = 0; j < 8; ++j)
        xb[pf][j] = (_Float16)xs[g * 8 + j][col];
    }
#pragma unroll
    for (int fo = 0; fo < 4; ++fo)
#pragma unroll
      for (int pf = 0; pf < NPF; ++pf)
        acc[fo][pf] = __builtin_amdgcn_mfma_f32_16x16x32_f16(
            a[fo], xb[pf], acc[fo][pf], 0, 0, 0);
  }
  __syncthreads();  // xs dead; smem becomes oT

  // epilogue: bias/act -> per-wave LDS transpose -> 16B vectorized stores
#pragma unroll
  for (int fo = 0; fo < 4; ++fo) {
#pragma unroll
    for (int r = 0; r < 4; ++r) {
      float bz = bias[oc0 + fo * 16 + g * 4 + r];
#pragma unroll
      for (int pf = 0; pf < NPF; ++pf) {
        float v = acc[fo][pf][r] + bz;
        if (ACT) v = fminf(fmaxf(v, 0.f), 6.f);
        oT[fo * 16 + g * 4 + r][wpx + pf * 16 + l15] = (TO)v;
      }
    }
  }
#pragma unroll
  for (int i = 0; i < LPO; ++i) {
    int oc = i * OCPI + lane / LPO;
    int pxo = (lane % LPO) * CH;
    vec16 v = *(const vec16*)&oT[oc][wpx + pxo];
    *(vec16*)&out[((size_t)b * OCT + oc0 + oc) * npx + p0 + wpx + pxo] = v;
  }
}

// ---------------------------------------------------------------- mask conv 5x5 s2 via MFMA + fused softmax
__global__ __launch_bounds__(256) void mask_conv6_k(
    const _Float16* __restrict__ y, const _Float16* __restrict__ wa,
    const float* __restrict__ be, float* __restrict__ msk) {
  __shared__ _Float16 ysh[32][5][136];
  __shared__ float lsm[32][66];
  const int ho = blockIdx.x;
  const int b = blockIdx.y;
  const int tid = threadIdx.x;
  const int lane = tid & 63;
  const int w = tid >> 6;
  const int l15 = lane & 15;
  const int g = lane >> 4;
  const int wo = w * 16 + l15;
  const int woe = (wo < 56) ? wo : 55;
  const int ci0 = 2 * woe + 6;

  for (int i = tid; i < 640; i += 256) {
    int ch = i / 20; int rem = i - ch * 20; int ri = rem / 4; int q = rem & 3;
    *(uint*)&ysh[ch][ri][q * 2] = 0u;
  }
  for (int i = tid; i < 1280; i += 256) {
    int ch = i / 40; int rem = i - ch * 40; int ri = rem / 8; int q = rem & 7;
    *(uint*)&ysh[ch][ri][120 + q * 2] = 0u;
  }

  f32x4 acc[2] = {(f32x4){0.f, 0.f, 0.f, 0.f}, (f32x4){0.f, 0.f, 0.f, 0.f}};

  for (int ph = 0; ph < 2; ++ph) {
    __syncthreads();
    for (int i = tid; i < 2240; i += 256) {
      int ch = i / 70;
      int rem = i - ch * 70;
      int ri = rem / 14;
      int j8 = rem - ri * 14;
      int hi = 2 * ho - 2 + ri;
      half8 v = {0, 0, 0, 0, 0, 0, 0, 0};
      if ((unsigned)hi < 112u)
        v = *(const half8*)&y[((size_t)(b * 64 + ph * 32 + ch) * 112 + hi) * 112 + j8 * 8];
      *(half8*)&ysh[ch][ri][8 + j8 * 8] = v;
    }
    __syncthreads();

    const _Float16* wap = wa + (size_t)ph * 25600;
#pragma unroll
    for (int di = 0; di < 5; ++di) {
      half2v pa[8], pb[8];
      _Float16 pc[8];
#pragma unroll
      for (int j = 0; j < 8; ++j) {
        pa[j] = *(const half2v*)&ysh[g * 8 + j][di][ci0];
        pb[j] = *(const half2v*)&ysh[g * 8 + j][di][ci0 + 2];
        pc[j] = ysh[g * 8 + j][di][ci0 + 4];
      }
#pragma unroll
      for (int dj = 0; dj < 5; ++dj) {
        half8 bf;
#pragma unroll
        for (int j = 0; j < 8; ++j)
          bf[j] = (dj == 0) ? pa[j][0]
                : (dj == 1) ? pa[j][1]
                : (dj == 2) ? pb[j][0]
                : (dj == 3) ? pb[j][1]
                            : pc[j];
        const int tap = di * 5 + dj;
        half8 a0 = *(const half8*)&wap[(tap * 2 + 0) * 512 + lane * 8];
        half8 a1 = *(const half8*)&wap[(tap * 2 + 1) * 512 + lane * 8];
        acc[0] = __builtin_amdgcn_mfma_f32_16x16x32_f16(a0, bf, acc[0], 0, 0, 0);
        acc[1] = __builtin_amdgcn_mfma_f32_16x16x32_f16(a1, bf, acc[1], 0, 0, 0);
      }
    }
  }

  // logits -> LDS
#pragma unroll
  for (int ocf = 0; ocf < 2; ++ocf)
#pragma unroll
    for (int r = 0; r < 4; ++r)
      lsm[ocf * 16 + g * 4 + r][w * 16 + l15] = acc[ocf][r];
  __syncthreads();

  // fused softmax over k=25 (threads 0..55 = wo)
  if (tid < 56) {
    float v[25];
    float mx = -1e30f;
#pragma unroll
    for (int k = 0; k < 25; ++k) {
      float s = lsm[k][tid] + be[k];
      v[k] = s;
      mx = fmaxf(mx, s);
    }
    float s = 0.f;
#pragma unroll
    for (int k = 0; k < 25; ++k) {
      v[k] = __expf(v[k] - mx);
      s += v[k];
    }
    float inv = 1.0f / s;
#pragma unroll
    for (int k = 0; k < 25; ++k)
      msk[((size_t)b * 25 + k) * 3136 + ho * 56 + tid] = v[k] * inv;
  }
}

// ---------------------------------------------------------------- carafe (f16 h in, f16 h2 out)
__device__ __forceinline__ void stage_pair(float dst[2][19][120],
                                           const _Float16* __restrict__ hbase,
                                           int ho0, int tid) {
  for (int i = tid; i < 2 * 19 * 14; i += 512) {
    int ch = i / 266;
    int rem = i - ch * 266;
    int rr = rem / 14;
    int j8 = rem - rr * 14;
    int hi = 2 * ho0 - 2 + rr;
    float4 lo = {0.f, 0.f, 0.f, 0.f}, hi4 = {0.f, 0.f, 0.f, 0.f};
    if ((unsigned)hi < 112u) {
      half8 v = *(const half8*)&hbase[(size_t)ch * 12544 + hi * 112 + j8 * 8];
      lo = (float4){(float)v[0], (float)v[1], (float)v[2], (float)v[3]};
      hi4 = (float4){(float)v[4], (float)v[5], (float)v[6], (float)v[7]};
    }
    *(float4*)&dst[ch][rr][4 + j8 * 8] = lo;
    *(float4*)&dst[ch][rr][8 + j8 * 8] = hi4;
  }
}

__global__ __launch_bounds__(512) void carafe3_k(
    const _Float16* __restrict__ h, const float* __restrict__ msk,
    const float* __restrict__ s2, const float* __restrict__ t2,
    _Float16* __restrict__ h2) {
  __shared__ float ys[2][2][19][120];
  const int hx = blockIdx.x;
  const int b  = blockIdx.y;
  const int cz = blockIdx.z;
  const int ho0 = hx * 8;
  const int tid = threadIdx.x;
  const int r = tid / 56;
  const int c = tid - r * 56;
  const int c0 = cz * 24;

  for (int i = tid; i < 2 * 2 * 19 * 8; i += 512) {
    int bufi = i / 304;
    int rem = i - bufi * 304;
    int ch = rem / 152;
    int rem2 = rem - ch * 152;
    int rr = rem2 / 8;
    int p = rem2 - rr * 8;
    int col = (p < 4) ? p : (112 + p);
    ys[bufi][ch][rr][col] = 0.f;
  }

  float m[25];
  if (tid < 448) {
    const float* mp = msk + (size_t)b * 25 * 3136 + (ho0 + r) * 56 + c;
#pragma unroll
    for (int k = 0; k < 25; ++k) m[k] = mp[(size_t)k * 3136];
  }
  __syncthreads();

  stage_pair(ys[0], h + (size_t)(b * 384 + c0) * 12544, ho0, tid);
  __syncthreads();

#pragma unroll
  for (int p = 0; p < 12; ++p) {
    const int bf = p & 1;
    if (p + 1 < 12)
      stage_pair(ys[bf ^ 1], h + (size_t)(b * 384 + c0 + 2 * (p + 1)) * 12544,
                 ho0, tid);
    if (tid < 448) {
#pragma unroll
      for (int cl = 0; cl < 2; ++cl) {
        const int cc = c0 + 2 * p + cl;
        float acc = 0.f;
#pragma unroll
        for (int di = 0; di < 5; ++di) {
          const float* row = &ys[bf][cl][2 * r + di][2 * c + 2];
          float2 a01 = *(const float2*)&row[0];
          float2 a23 = *(const float2*)&row[2];
          float a4 = row[4];
          acc = fmaf(a01.x, m[di * 5 + 0], acc);
          acc = fmaf(a01.y, m[di * 5 + 1], acc);
          acc = fmaf(a23.x, m[di * 5 + 2], acc);
          acc = fmaf(a23.y, m[di * 5 + 3], acc);
          acc = fmaf(a4,    m[di * 5 + 4], acc);
        }
        float o = s2[cc] * acc + t2[cc];
        h2[((size_t)(b * 384 + cc) * 56 + ho0 + r) * 56 + c] =
            (_Float16)fminf(fmaxf(o, 0.f), 6.f);
      }
    }
    __syncthreads();
  }
}

// ---------------------------------------------------------------- launch
extern "C" void kernel_launch(void* const* d_in, const int* in_sizes, int n_in,
                              void* d_out, int out_size, void* d_ws, size_t ws_size,
                              hipStream_t stream) {
  const float* x  = (const float*)d_in[0];
  const float* w1 = (const float*)d_in[1];
  const float* g1 = (const float*)d_in[2];
  const float* b1 = (const float*)d_in[3];
  const float* m1 = (const float*)d_in[4];
  const float* v1 = (const float*)d_in[5];
  const float* wc = (const float*)d_in[6];
  const float* bc = (const float*)d_in[7];
  const float* we = (const float*)d_in[8];
  const float* be = (const float*)d_in[9];
  const float* g2 = (const float*)d_in[10];
  const float* b2 = (const float*)d_in[11];
  const float* m2 = (const float*)d_in[12];
  const float* v2 = (const float*)d_in[13];
  const float* w2 = (const float*)d_in[14];
  const float* g3 = (const float*)d_in[15];
  const float* b3 = (const float*)d_in[16];
  const float* m3 = (const float*)d_in[17];
  const float* v3 = (const float*)d_in[18];
  float* out = (float*)d_out;

  // workspace layout
  _Float16* hq  = (_Float16*)d_ws;          // 38,535,168 halves
  _Float16* yq  = hq + 38535168;            //  6,422,528 halves
  _Float16* h2q = yq + 6422528;             //  9,633,792 halves
  float* mskf   = (float*)(h2q + 9633792);  //    627,200 floats
  float* bias1  = mskf + 627200;            // 384
  float* bias3  = bias1 + 384;              // 128
  float* s2     = bias3 + 128;              // 384
  float* t2     = s2 + 384;                 // 384
  _Float16* w1h = (_Float16*)(t2 + 384);    // 24576 halves
  _Float16* wch = w1h + 24576;              // 24576 halves
  _Float16* w2h = wch + 24576;              // 49152 halves
  _Float16* wa  = w2h + 49152;              // 51200 halves (MFMA A-frags)

  fold_k<<<200, 256, 0, stream>>>(w1, g1, b1, m1, v1, wc, g2, b2, m2, v2,
                                  w2, g3, b3, m3, v3, we,
                                  w1h, bias1, wch, w2h, bias3, s2, t2, wa);

  // stage 1: h = relu6(bn1(conv1x1(x, w1)))  [fp32 in, f16 out]
  gemm16_k<64, 2, 1, 6, 98, float, _Float16>
      <<<6 * 98 * 8, 256, 0, stream>>>(x, w1h, bias1, hq, 12544);

  // compressor: y = conv1x1(h, wc) + bc  [f16 in, f16 out]
  gemm16_k<384, 2, 0, 1, 98, _Float16, _Float16>
      <<<1 * 98 * 8, 256, 0, stream>>>(hq, wch, bc, yq, 12544);

  // mask conv via MFMA + in-kernel softmax
  mask_conv6_k<<<dim3(56, 8), 256, 0, stream>>>(yq, wa, be, mskf);

  // carafe + bn2 + relu6  [f16 in/out]
  carafe3_k<<<dim3(7, 8, 16), 512, 0, stream>>>(hq, mskf, s2, t2, h2q);

  // final: out = bn3(conv1x1(h2, w2))  [f16 in, fp32 out]
  gemm16_k<384, 1, 0, 2, 49, _Float16, float>
      <<<2 * 49 * 8, 256, 0, stream>>>(h2q, w2h, bias3, out, 3136);
}